// Round 1
// baseline (691.351 us; speedup 1.0000x reference)
//
#include <hip/hip_runtime.h>

#define NUM_USER   4096
#define NUM_ITEM   16384
#define NUM_HIDDEN 64
#define B_SZ       1024
#define L_SZ       50
#define KROWS      64   // max batch rows tracked per user (P(overflow) ~ 0 for random 1024 draws into 4096 bins)

// Bucket batch rows by user id so the scatter kernel can find all rows sharing its user.
__global__ void build_rows_kernel(const int* __restrict__ idx_user,
                                  int* __restrict__ user_count,
                                  int* __restrict__ user_rows) {
    int b = blockIdx.x * blockDim.x + threadIdx.x;
    if (b < B_SZ) {
        int u = idx_user[b];
        int slot = atomicAdd(&user_count[u], 1);
        if (slot < KROWS) user_rows[u * KROWS + slot] = b;
    }
}

// One wave (64 lanes) per (b,l) pair: lane h holds hidden-dim h of the dot product.
// Lanes 0..49 also check duplicate (u,item) pairs with LATER sequence number in
// parallel; ballot decides whether this pair is the numpy last-write winner.
__global__ void scatter_kernel(const int* __restrict__ idx_user,
                               const int* __restrict__ item_sets,
                               const float* __restrict__ rating_sets,
                               const float* __restrict__ embed_user,
                               const float* __restrict__ embed_item,
                               float* __restrict__ pred_mask,
                               float* __restrict__ label,
                               const int* __restrict__ user_count,
                               const int* __restrict__ user_rows,
                               unsigned int* __restrict__ ucount) {
    const int p    = blockIdx.x;          // pair index 0 .. B*L-1, seq order == numpy C-order
    const int b    = p / L_SZ;
    const int l    = p - b * L_SZ;
    const int lane = threadIdx.x;         // 0..63

    const int u  = idx_user[b];
    const int it = item_sets[p];

    // 64-wide dot product: lane h multiplies element h, butterfly reduce across the wave.
    float a = embed_user[u * NUM_HIDDEN + lane];
    float c = embed_item[it * NUM_HIDDEN + lane];
    float v = a * c;
    #pragma unroll
    for (int m = 32; m >= 1; m >>= 1) v += __shfl_xor(v, m, 64);

    // Duplicate detection: does any pair with larger seq (same row later l, or later row
    // of the same user) target the same item? Lanes 0..49 each check one item slot.
    bool dup = false;
    if (lane > l && lane < L_SZ) dup = (item_sets[b * L_SZ + lane] == it);
    int cnt = user_count[u];
    if (cnt > KROWS) cnt = KROWS;
    for (int s = 0; s < cnt; ++s) {
        int b2 = user_rows[u * KROWS + s];
        if (b2 > b && lane < L_SZ) dup |= (item_sets[b2 * L_SZ + lane] == it);
    }
    unsigned long long anydup = __ballot(dup);

    if (lane == 0) {
        size_t cell = (size_t)u * NUM_ITEM + it;
        // pred value is identical for all duplicates of (u,it) -> unconditional store is safe.
        pred_mask[cell] = v;
        if (anydup == 0ull) {
            // This pair is the last writer in numpy order -> its rating wins.
            label[cell] = rating_sets[p];
            atomicAdd(ucount, 1u);   // counts unique (u,it) cells == sum(mask)
        }
    }
}

__global__ void sparsity_kernel(const unsigned int* __restrict__ ucount,
                                float* __restrict__ out) {
    if (threadIdx.x == 0 && blockIdx.x == 0) {
        out[0] = (float)((double)NUM_USER * (double)NUM_ITEM / (double)(*ucount));
    }
}

extern "C" void kernel_launch(void* const* d_in, const int* in_sizes, int n_in,
                              void* d_out, int out_size, void* d_ws, size_t ws_size,
                              hipStream_t stream) {
    const int*   idx_user    = (const int*)d_in[0];
    const int*   item_sets   = (const int*)d_in[1];
    const float* rating_sets = (const float*)d_in[2];
    const float* embed_user  = (const float*)d_in[3];
    const float* embed_item  = (const float*)d_in[4];

    float* pred_mask = (float*)d_out;
    float* label     = pred_mask + (size_t)NUM_USER * NUM_ITEM;
    float* sparsity  = label     + (size_t)NUM_USER * NUM_ITEM;

    int*          user_count = (int*)d_ws;
    int*          user_rows  = user_count + NUM_USER;
    unsigned int* ucount     = (unsigned int*)(user_rows + (size_t)NUM_USER * KROWS);

    // Output is dense zeros + 51200 scattered values: zero it every call
    // (harness poisons once; graph replays must be deterministic).
    hipMemsetAsync(d_out, 0, (size_t)out_size * sizeof(float), stream);
    hipMemsetAsync(d_ws, 0, (size_t)(NUM_USER * (KROWS + 1) + 1) * sizeof(int), stream);

    build_rows_kernel<<<(B_SZ + 255) / 256, 256, 0, stream>>>(idx_user, user_count, user_rows);
    scatter_kernel<<<B_SZ * L_SZ, 64, 0, stream>>>(idx_user, item_sets, rating_sets,
                                                   embed_user, embed_item,
                                                   pred_mask, label,
                                                   user_count, user_rows, ucount);
    sparsity_kernel<<<1, 64, 0, stream>>>(ucount, sparsity);
}

// Round 2
// 129.396 us; speedup vs baseline: 5.3429x; 5.3429x over previous
//
#include <hip/hip_runtime.h>

#define NUM_USER   4096
#define NUM_ITEM   16384
#define NUM_HIDDEN 64
#define B_SZ       1024
#define L_SZ       50
#define KROWS      64    // max batch rows tracked per user (P(overflow) ~ 0 for 1024 draws into 4096 bins)
#define NBUCKET    1024  // spread the unique-pair count across buckets to kill atomic contention

// Bucket batch rows by user id so the scatter kernel can find all rows sharing its user.
__global__ void build_rows_kernel(const int* __restrict__ idx_user,
                                  int* __restrict__ user_count,
                                  int* __restrict__ user_rows) {
    int b = blockIdx.x * blockDim.x + threadIdx.x;
    if (b < B_SZ) {
        int u = idx_user[b];
        int slot = atomicAdd(&user_count[u], 1);
        if (slot < KROWS) user_rows[u * KROWS + slot] = b;
    }
}

// One wave (64 lanes) per (b,l) pair: lane h holds hidden-dim h of the dot product.
// Lanes 0..49 also check duplicate (u,item) pairs with LATER sequence number in
// parallel; ballot decides whether this pair is the numpy last-write winner.
__global__ void scatter_kernel(const int* __restrict__ idx_user,
                               const int* __restrict__ item_sets,
                               const float* __restrict__ rating_sets,
                               const float* __restrict__ embed_user,
                               const float* __restrict__ embed_item,
                               float* __restrict__ pred_mask,
                               float* __restrict__ label,
                               const int* __restrict__ user_count,
                               const int* __restrict__ user_rows,
                               unsigned int* __restrict__ ucount) {
    const int p    = blockIdx.x;          // pair index 0 .. B*L-1, seq order == numpy C-order
    const int b    = p / L_SZ;
    const int l    = p - b * L_SZ;
    const int lane = threadIdx.x;         // 0..63

    const int u  = idx_user[b];
    const int it = item_sets[p];

    // 64-wide dot product: lane h multiplies element h, butterfly reduce across the wave.
    float a = embed_user[u * NUM_HIDDEN + lane];
    float c = embed_item[it * NUM_HIDDEN + lane];
    float v = a * c;
    #pragma unroll
    for (int m = 32; m >= 1; m >>= 1) v += __shfl_xor(v, m, 64);

    // Duplicate detection: does any pair with larger seq (same row later l, or later row
    // of the same user) target the same item? Lanes 0..49 each check one item slot.
    bool dup = false;
    if (lane > l && lane < L_SZ) dup = (item_sets[b * L_SZ + lane] == it);
    int cnt = user_count[u];
    if (cnt > KROWS) cnt = KROWS;
    for (int s = 0; s < cnt; ++s) {
        int b2 = user_rows[u * KROWS + s];
        if (b2 > b && lane < L_SZ) dup |= (item_sets[b2 * L_SZ + lane] == it);
    }
    unsigned long long anydup = __ballot(dup);

    if (lane == 0) {
        size_t cell = (size_t)u * NUM_ITEM + it;
        // pred value is identical for all duplicates of (u,it) -> unconditional store is safe.
        pred_mask[cell] = v;
        if (anydup == 0ull) {
            // This pair is the last writer in numpy order -> its rating wins.
            label[cell] = rating_sets[p];
            // Bucketed count of unique (u,it) cells: ~50 atomics/bucket, no contention.
            atomicAdd(&ucount[p & (NBUCKET - 1)], 1u);
        }
    }
}

// One block: reduce the NBUCKET partial counts, emit sparsity scalar.
__global__ void sparsity_kernel(const unsigned int* __restrict__ ucount,
                                float* __restrict__ out) {
    __shared__ unsigned int warp_sum[4];
    const int t = threadIdx.x;            // 256 threads = 4 waves
    unsigned int s = 0;
    #pragma unroll
    for (int i = 0; i < NBUCKET / 256; ++i) s += ucount[t + i * 256];
    #pragma unroll
    for (int m = 32; m >= 1; m >>= 1) s += __shfl_xor(s, m, 64);
    if ((t & 63) == 0) warp_sum[t >> 6] = s;
    __syncthreads();
    if (t == 0) {
        unsigned int total = warp_sum[0] + warp_sum[1] + warp_sum[2] + warp_sum[3];
        out[0] = (float)((double)NUM_USER * (double)NUM_ITEM / (double)total);
    }
}

extern "C" void kernel_launch(void* const* d_in, const int* in_sizes, int n_in,
                              void* d_out, int out_size, void* d_ws, size_t ws_size,
                              hipStream_t stream) {
    const int*   idx_user    = (const int*)d_in[0];
    const int*   item_sets   = (const int*)d_in[1];
    const float* rating_sets = (const float*)d_in[2];
    const float* embed_user  = (const float*)d_in[3];
    const float* embed_item  = (const float*)d_in[4];

    float* pred_mask = (float*)d_out;
    float* label     = pred_mask + (size_t)NUM_USER * NUM_ITEM;
    float* sparsity  = label     + (size_t)NUM_USER * NUM_ITEM;

    int*          user_count = (int*)d_ws;
    int*          user_rows  = user_count + NUM_USER;
    unsigned int* ucount     = (unsigned int*)(user_rows + (size_t)NUM_USER * KROWS);

    // Output is dense zeros + 51200 scattered values: zero it every call
    // (harness poisons once; graph replays must be deterministic).
    hipMemsetAsync(d_out, 0, (size_t)out_size * sizeof(float), stream);
    hipMemsetAsync(d_ws, 0, (size_t)(NUM_USER * (KROWS + 1) + NBUCKET) * sizeof(int), stream);

    build_rows_kernel<<<(B_SZ + 255) / 256, 256, 0, stream>>>(idx_user, user_count, user_rows);
    scatter_kernel<<<B_SZ * L_SZ, 64, 0, stream>>>(idx_user, item_sets, rating_sets,
                                                   embed_user, embed_item,
                                                   pred_mask, label,
                                                   user_count, user_rows, ucount);
    sparsity_kernel<<<1, 256, 0, stream>>>(ucount, sparsity);
}